// Round 7
// baseline (588.337 us; speedup 1.0000x reference)
//
#include <hip/hip_runtime.h>
#include <hip/hip_cooperative_groups.h>

namespace cg = cooperative_groups;

// GCN autoencoder: recon = (Z @ Z^T)
//   h  = X @ W1   (10000x512 @ 512x32)
//   h1 = relu(A @ h);  h2 = h1 @ W2   (fused, h1 stays in LDS)
//   z  = A @ h2
//   out= z @ z^T  (1e8 f32, 400 MB -> HBM-write-bound, ~58 us floor)
//
// R7: R6 measured zzt marginal = 118 us -> front-end (4 kernels) = ~98 us,
// and every cross-round delta fits dur = sum(exec) + ~16us/node. So: fuse the
// whole front-end into ONE cooperative kernel (grid.sync between phases,
// 1024 co-resident blocks, all phases grid-stride). 2 nodes total.
// zzt kept bit-for-bit R4 (isolate the variable; its rewrite is next).

constexpr int N_   = 10000;
constexpr int E_   = 320000;
constexpr int F_   = 512;
constexpr int H1_  = 32;
constexpr int H2_  = 16;
constexpr int CAP_ = 96;   // ELL row capacity; P[Poisson(32) > 96] ~ 3e-20

constexpr int COOP_BLOCKS = 1024;   // 4 blocks/CU -> co-resident guaranteed

// ---------------- K1: fused front-end (cooperative) ----------------
__global__ __launch_bounds__(256) void fused_front(const float* __restrict__ x,
                                                   const float* __restrict__ W1,
                                                   const float* __restrict__ W2,
                                                   const float* __restrict__ ew,
                                                   const int* __restrict__ erow,
                                                   const int* __restrict__ ecol,
                                                   float* __restrict__ h,
                                                   float* __restrict__ h2,
                                                   float* __restrict__ z,
                                                   int* __restrict__ cursor,
                                                   int* __restrict__ cole,
                                                   float* __restrict__ we) {
    cg::grid_group grid = cg::this_grid();
    const int t     = threadIdx.x;
    const int gtid  = blockIdx.x * 256 + t;
    const int gsize = gridDim.x * 256;

    // ---- P1: zero cursor + h = X @ W1 ----
    for (int i = gtid; i < N_; i += gsize) cursor[i] = 0;
    for (int tid = gtid; tid < N_ * H1_; tid += gsize) {
        int r = tid >> 5;            // /32
        int c = tid & (H1_ - 1);
        const float4* xr = reinterpret_cast<const float4*>(x + (size_t)r * F_);
        float acc = 0.f;
#pragma unroll 8
        for (int k4 = 0; k4 < F_ / 4; ++k4) {
            float4 xv = xr[k4];
            int k = k4 * 4;
            acc = fmaf(xv.x, W1[(k + 0) * H1_ + c], acc);
            acc = fmaf(xv.y, W1[(k + 1) * H1_ + c], acc);
            acc = fmaf(xv.z, W1[(k + 2) * H1_ + c], acc);
            acc = fmaf(xv.w, W1[(k + 3) * H1_ + c], acc);
        }
        h[tid] = acc;
    }
    grid.sync();

    // ---- P2: scatter edges into ELL rows ----
    for (int e = gtid; e < E_; e += gsize) {
        int r = erow[e];
        int p = atomicAdd(&cursor[r], 1);
        if (p < CAP_) {
            size_t idx = (size_t)r * CAP_ + p;
            cole[idx] = ecol[e];
            we[idx]   = ew[e];
        }
    }
    grid.sync();

    // ---- P3: h2 = relu(A @ h) @ W2  (8 rows per block-iteration) ----
    __shared__ float sh1[8][H1_ + 1];
    __shared__ float sW2[H1_ * H2_];
    sW2[t]       = W2[t];
    sW2[t + 256] = W2[t + 256];
    __syncthreads();

    constexpr int NGROUP1 = (N_ + 7) / 8;     // 1250
    for (int g = blockIdx.x; g < NGROUP1; g += gridDim.x) {
        __syncthreads();                      // sh1 reuse across iterations
        const int rl = t >> 5;                // 0..7
        const int f  = t & (H1_ - 1);
        const int r  = g * 8 + rl;
        float acc = 0.f;
        if (r < N_) {
            const int deg = cursor[r];
            const int*   cp = cole + (size_t)r * CAP_;
            const float* wp = we   + (size_t)r * CAP_;
            int p = 0;
            for (; p + 4 <= deg; p += 4) {
                int c0 = cp[p], c1 = cp[p + 1], c2 = cp[p + 2], c3 = cp[p + 3];
                float w0 = wp[p], w1 = wp[p + 1], w2v = wp[p + 2], w3 = wp[p + 3];
                float g0 = h[(size_t)c0 * H1_ + f];
                float g1 = h[(size_t)c1 * H1_ + f];
                float g2 = h[(size_t)c2 * H1_ + f];
                float g3 = h[(size_t)c3 * H1_ + f];
                acc = fmaf(w0, g0, acc);
                acc = fmaf(w1, g1, acc);
                acc = fmaf(w2v, g2, acc);
                acc = fmaf(w3, g3, acc);
            }
            for (; p < deg; ++p)
                acc = fmaf(wp[p], h[(size_t)cp[p] * H1_ + f], acc);
        }
        sh1[rl][f] = fmaxf(acc, 0.f);         // relu fused
        __syncthreads();
        if (t < 128) {
            const int r2l = t >> 4;           // 0..7
            const int c   = t & (H2_ - 1);
            const int r2  = g * 8 + r2l;
            if (r2 < N_) {
                float a = 0.f;
#pragma unroll
                for (int k = 0; k < H1_; ++k)
                    a = fmaf(sh1[r2l][k], sW2[k * H2_ + c], a);
                h2[(size_t)r2 * H2_ + c] = a;
            }
        }
    }
    grid.sync();

    // ---- P4: z = A @ h2  (16 rows per block-iteration, no LDS) ----
    constexpr int NGROUP2 = (N_ + 15) / 16;   // 625
    for (int g = blockIdx.x; g < NGROUP2; g += gridDim.x) {
        const int rl = t >> 4;                // 0..15
        const int f  = t & (H2_ - 1);
        const int r  = g * 16 + rl;
        if (r >= N_) continue;
        const int deg = cursor[r];
        const int*   cp = cole + (size_t)r * CAP_;
        const float* wp = we   + (size_t)r * CAP_;
        float acc = 0.f;
        int p = 0;
        for (; p + 4 <= deg; p += 4) {
            int c0 = cp[p], c1 = cp[p + 1], c2 = cp[p + 2], c3 = cp[p + 3];
            float w0 = wp[p], w1 = wp[p + 1], w2v = wp[p + 2], w3 = wp[p + 3];
            float g0 = h2[(size_t)c0 * H2_ + f];
            float g1 = h2[(size_t)c1 * H2_ + f];
            float g2 = h2[(size_t)c2 * H2_ + f];
            float g3 = h2[(size_t)c3 * H2_ + f];
            acc = fmaf(w0, g0, acc);
            acc = fmaf(w1, g1, acc);
            acc = fmaf(w2v, g2, acc);
            acc = fmaf(w3, g3, acc);
        }
        for (; p < deg; ++p)
            acc = fmaf(wp[p], h2[(size_t)cp[p] * H2_ + f], acc);
        z[(size_t)r * H2_ + f] = acc;
    }
}

// ---------------- K2: out = z @ z^T  (R4 tile version, fire-and-forget) ----
constexpr int BI = 32;
constexpr int BJ = 128;

__global__ __launch_bounds__(256) void zzt(const float* __restrict__ z,
                                           float* __restrict__ out) {
    __shared__ float zi[H2_][BI + 4];
    __shared__ float zj[H2_][BJ + 4];
    const int t  = threadIdx.x;
    const int ib = blockIdx.y * BI;
    const int jb = blockIdx.x * BJ;

    for (int idx = t; idx < BI * H2_; idx += 256) {
        int rl = idx >> 4;
        int k  = idx & 15;
        int gr = ib + rl;
        zi[k][rl] = (gr < N_) ? z[(size_t)gr * H2_ + k] : 0.f;
    }
    for (int idx = t; idx < BJ * H2_; idx += 256) {
        int rl = idx >> 4;
        int k  = idx & 15;
        int gr = jb + rl;
        zj[k][rl] = (gr < N_) ? z[(size_t)gr * H2_ + k] : 0.f;
    }
    __syncthreads();

    const int il = (t >> 5) << 2;   // 0,4,...,28
    const int jl = (t & 31) << 2;   // 0,4,...,124

    float acc[4][4] = {};
#pragma unroll
    for (int k = 0; k < H2_; ++k) {
        float4 a = *reinterpret_cast<const float4*>(&zi[k][il]);
        float4 b = *reinterpret_cast<const float4*>(&zj[k][jl]);
        acc[0][0] = fmaf(a.x, b.x, acc[0][0]);
        acc[0][1] = fmaf(a.x, b.y, acc[0][1]);
        acc[0][2] = fmaf(a.x, b.z, acc[0][2]);
        acc[0][3] = fmaf(a.x, b.w, acc[0][3]);
        acc[1][0] = fmaf(a.y, b.x, acc[1][0]);
        acc[1][1] = fmaf(a.y, b.y, acc[1][1]);
        acc[1][2] = fmaf(a.y, b.z, acc[1][2]);
        acc[1][3] = fmaf(a.y, b.w, acc[1][3]);
        acc[2][0] = fmaf(a.z, b.x, acc[2][0]);
        acc[2][1] = fmaf(a.z, b.y, acc[2][1]);
        acc[2][2] = fmaf(a.z, b.z, acc[2][2]);
        acc[2][3] = fmaf(a.z, b.w, acc[2][3]);
        acc[3][0] = fmaf(a.w, b.x, acc[3][0]);
        acc[3][1] = fmaf(a.w, b.y, acc[3][1]);
        acc[3][2] = fmaf(a.w, b.z, acc[3][2]);
        acc[3][3] = fmaf(a.w, b.w, acc[3][3]);
    }

#pragma unroll
    for (int ii = 0; ii < 4; ++ii) {
        int gi = ib + il + ii;
        if (gi >= N_) continue;
        int gj = jb + jl;
        float* orow = out + (size_t)gi * N_ + gj;
        if (gj + 3 < N_) {
            *reinterpret_cast<float4*>(orow) =
                make_float4(acc[ii][0], acc[ii][1], acc[ii][2], acc[ii][3]);
        } else {
#pragma unroll
            for (int jj = 0; jj < 4; ++jj)
                if (gj + jj < N_) orow[jj] = acc[ii][jj];
        }
    }
}

extern "C" void kernel_launch(void* const* d_in, const int* in_sizes, int n_in,
                              void* d_out, int out_size, void* d_ws, size_t ws_size,
                              hipStream_t stream) {
    const float* x    = (const float*)d_in[0];
    const float* ew   = (const float*)d_in[1];
    const float* W1   = (const float*)d_in[2];
    const float* W2   = (const float*)d_in[3];
    const int*   erow = (const int*)d_in[4];
    const int*   ecol = (const int*)d_in[5];
    float* out = (float*)d_out;

    // workspace layout (4B elements)
    float* h      = (float*)d_ws;              // N*H1
    float* h2     = h  + (size_t)N_ * H1_;     // N*H2
    float* z      = h2 + (size_t)N_ * H2_;     // N*H2
    float* we     = z  + (size_t)N_ * H2_;     // N*CAP
    int*   cole   = (int*)(we + (size_t)N_ * CAP_);   // N*CAP
    int*   cursor = cole + (size_t)N_ * CAP_;  // N

    void* args[] = {(void*)&x, (void*)&W1, (void*)&W2, (void*)&ew,
                    (void*)&erow, (void*)&ecol,
                    (void*)&h, (void*)&h2, (void*)&z,
                    (void*)&cursor, (void*)&cole, (void*)&we};
    hipLaunchCooperativeKernel((const void*)fused_front, dim3(COOP_BLOCKS),
                               dim3(256), args, 0, stream);

    dim3 grid((N_ + BJ - 1) / BJ, (N_ + BI - 1) / BI);
    zzt<<<grid, 256, 0, stream>>>(z, out);
}

// Round 8
// 282.498 us; speedup vs baseline: 2.0826x; 2.0826x over previous
//
#include <hip/hip_runtime.h>

// GCN autoencoder: recon = (Z @ Z^T)
//   h  = X @ W1   (10000x512 @ 512x32)
//   h1 = A @ h    (raw sums; relu deferred to consumer)
//   z  = A @ (relu(h1) @ W2)   (W2-MLP inlined per edge)
//   out= z @ z^T  (1e8 f32, 400 MB -> HBM-write-bound, ~58-63 us floor)
//
// R8. Model (R6/R7-validated): dur = sum(exec) + ~16us/node; grid.sync costs
// ~140us/sync on 8 non-coherent L2s (R7: 470us, 97% idle) -> dead end.
// So: minimize nodes WITHOUT grid sync. 4 nodes:
//   K1 gemm_xw1 + zero(h1,z)   (split grid)
//   K2 spmm1 atomic (edge-parallel; R2 proved ~10us-class exec)
//   K3 spmm2 atomic + inline W2-MLP (recompute h2[c] per edge: 32 FMA/thread,
//      ~164M FMA total ~ trivial; kills the separate h1w2 node)
//   K4 zzt: zi register-cached (64 VGPR) -> LDS traffic halved, shorter
//      per-k dependent chain. Stores unchanged fire-and-forget.

constexpr int N_   = 10000;
constexpr int E_   = 320000;
constexpr int F_   = 512;
constexpr int H1_  = 32;
constexpr int H2_  = 16;

// ---------------- K1: h = X @ W1, side blocks zero h1|z ----------------
constexpr int GEMM_BLOCKS = (N_ * H1_) / 256;                    // 1250
constexpr int ZERO_FLOATS = N_ * H1_ + N_ * H2_;                 // h1|z adjacent
constexpr int ZERO_BLOCKS = (ZERO_FLOATS / 4 + 255) / 256;       // 469

__global__ __launch_bounds__(256) void gemm_xw1_zero(const float* __restrict__ x,
                                                     const float* __restrict__ W1,
                                                     float* __restrict__ h,
                                                     float4* __restrict__ zero_base) {
    if (blockIdx.x >= GEMM_BLOCKS) {
        int i = (blockIdx.x - GEMM_BLOCKS) * 256 + threadIdx.x;
        if (i < ZERO_FLOATS / 4) zero_base[i] = make_float4(0.f, 0.f, 0.f, 0.f);
        return;
    }
    int tid = blockIdx.x * blockDim.x + threadIdx.x;
    int r = tid >> 5;          // /32
    int c = tid & (H1_ - 1);
    const float4* xr = reinterpret_cast<const float4*>(x + (size_t)r * F_);
    float acc = 0.f;
#pragma unroll 8
    for (int k4 = 0; k4 < F_ / 4; ++k4) {
        float4 xv = xr[k4];
        int k = k4 * 4;
        acc = fmaf(xv.x, W1[(k + 0) * H1_ + c], acc);
        acc = fmaf(xv.y, W1[(k + 1) * H1_ + c], acc);
        acc = fmaf(xv.z, W1[(k + 2) * H1_ + c], acc);
        acc = fmaf(xv.w, W1[(k + 3) * H1_ + c], acc);
    }
    h[tid] = acc;
}

// ---------------- K2: h1[r] += w * h[c]  (edge-parallel, 32 f/edge) --------
__global__ __launch_bounds__(256) void spmm1_atomic(const float* __restrict__ h,
                                                    const float* __restrict__ ew,
                                                    const int* __restrict__ erow,
                                                    const int* __restrict__ ecol,
                                                    float* __restrict__ h1) {
    int tid = blockIdx.x * blockDim.x + threadIdx.x;
    if (tid >= E_ * H1_) return;
    int e = tid >> 5;
    int f = tid & (H1_ - 1);
    int r = erow[e];
    int c = ecol[e];
    float v = ew[e] * h[(size_t)c * H1_ + f];
    atomicAdd(&h1[(size_t)r * H1_ + f], v);
}

// ---------------- K3: z[r] += w * (relu(h1[c]) @ W2)  (16 f/edge) ----------
__global__ __launch_bounds__(256) void spmm2_mlp(const float* __restrict__ h1,
                                                 const float* __restrict__ W2,
                                                 const float* __restrict__ ew,
                                                 const int* __restrict__ erow,
                                                 const int* __restrict__ ecol,
                                                 float* __restrict__ z) {
    __shared__ float sW2[H1_ * H2_];
    const int t = threadIdx.x;
    sW2[t]       = W2[t];
    sW2[t + 256] = W2[t + 256];
    __syncthreads();

    int tid = blockIdx.x * blockDim.x + t;
    if (tid >= E_ * H2_) return;
    int e = tid >> 4;
    int f = tid & (H2_ - 1);
    int r = erow[e];
    int c = ecol[e];
    const float* h1r = h1 + (size_t)c * H1_;
    float acc = 0.f;
#pragma unroll
    for (int k = 0; k < H1_; ++k)
        acc = fmaf(fmaxf(h1r[k], 0.f), sW2[k * H2_ + f], acc);
    atomicAdd(&z[(size_t)r * H2_ + f], ew[e] * acc);
}

// ---------------- K4: out = z @ z^T  (zi in registers, zj in LDS) ----------
constexpr int BI = 32;
constexpr int BJ = 128;

__global__ __launch_bounds__(256) void zzt(const float* __restrict__ z,
                                           float* __restrict__ out) {
    __shared__ float zj[H2_][BJ + 4];
    const int t  = threadIdx.x;
    const int ib = blockIdx.y * BI;
    const int jb = blockIdx.x * BJ;

    const int il = (t >> 5) << 2;   // 0,4,...,28
    const int jl = (t & 31) << 2;   // 0,4,...,124

    // zi -> registers: this thread's 4 i-rows x 16 k (64 VGPR).
    float zr0[16], zr1[16], zr2[16], zr3[16];
#pragma unroll
    for (int kq = 0; kq < 4; ++kq) {
        int r0 = ib + il;
        *reinterpret_cast<float4*>(&zr0[kq * 4]) = (r0 + 0 < N_)
            ? *reinterpret_cast<const float4*>(z + (size_t)(r0 + 0) * H2_ + kq * 4)
            : make_float4(0.f, 0.f, 0.f, 0.f);
        *reinterpret_cast<float4*>(&zr1[kq * 4]) = (r0 + 1 < N_)
            ? *reinterpret_cast<const float4*>(z + (size_t)(r0 + 1) * H2_ + kq * 4)
            : make_float4(0.f, 0.f, 0.f, 0.f);
        *reinterpret_cast<float4*>(&zr2[kq * 4]) = (r0 + 2 < N_)
            ? *reinterpret_cast<const float4*>(z + (size_t)(r0 + 2) * H2_ + kq * 4)
            : make_float4(0.f, 0.f, 0.f, 0.f);
        *reinterpret_cast<float4*>(&zr3[kq * 4]) = (r0 + 3 < N_)
            ? *reinterpret_cast<const float4*>(z + (size_t)(r0 + 3) * H2_ + kq * 4)
            : make_float4(0.f, 0.f, 0.f, 0.f);
    }

    // zj -> LDS transposed [k][row]: 2 threads per row, float4 global loads,
    // 2-way-aliased LDS writes (free per m136).
    {
        const int rl    = t >> 1;            // 0..127
        const int khalf = (t & 1) * 8;       // 0 or 8
        const int gr    = jb + rl;
        float4 v0, v1;
        if (gr < N_) {
            v0 = *reinterpret_cast<const float4*>(z + (size_t)gr * H2_ + khalf);
            v1 = *reinterpret_cast<const float4*>(z + (size_t)gr * H2_ + khalf + 4);
        } else {
            v0 = v1 = make_float4(0.f, 0.f, 0.f, 0.f);
        }
        zj[khalf + 0][rl] = v0.x;
        zj[khalf + 1][rl] = v0.y;
        zj[khalf + 2][rl] = v0.z;
        zj[khalf + 3][rl] = v0.w;
        zj[khalf + 4][rl] = v1.x;
        zj[khalf + 5][rl] = v1.y;
        zj[khalf + 6][rl] = v1.z;
        zj[khalf + 7][rl] = v1.w;
    }
    __syncthreads();

    float acc[4][4] = {};
#pragma unroll
    for (int k = 0; k < H2_; ++k) {
        float4 b = *reinterpret_cast<const float4*>(&zj[k][jl]);
        float a0 = zr0[k], a1 = zr1[k], a2 = zr2[k], a3 = zr3[k];
        acc[0][0] = fmaf(a0, b.x, acc[0][0]);
        acc[0][1] = fmaf(a0, b.y, acc[0][1]);
        acc[0][2] = fmaf(a0, b.z, acc[0][2]);
        acc[0][3] = fmaf(a0, b.w, acc[0][3]);
        acc[1][0] = fmaf(a1, b.x, acc[1][0]);
        acc[1][1] = fmaf(a1, b.y, acc[1][1]);
        acc[1][2] = fmaf(a1, b.z, acc[1][2]);
        acc[1][3] = fmaf(a1, b.w, acc[1][3]);
        acc[2][0] = fmaf(a2, b.x, acc[2][0]);
        acc[2][1] = fmaf(a2, b.y, acc[2][1]);
        acc[2][2] = fmaf(a2, b.z, acc[2][2]);
        acc[2][3] = fmaf(a2, b.w, acc[2][3]);
        acc[3][0] = fmaf(a3, b.x, acc[3][0]);
        acc[3][1] = fmaf(a3, b.y, acc[3][1]);
        acc[3][2] = fmaf(a3, b.z, acc[3][2]);
        acc[3][3] = fmaf(a3, b.w, acc[3][3]);
    }

#pragma unroll
    for (int ii = 0; ii < 4; ++ii) {
        int gi = ib + il + ii;
        if (gi >= N_) continue;
        int gj = jb + jl;
        float* orow = out + (size_t)gi * N_ + gj;
        if (gj + 3 < N_) {
            *reinterpret_cast<float4*>(orow) =
                make_float4(acc[ii][0], acc[ii][1], acc[ii][2], acc[ii][3]);
        } else {
#pragma unroll
            for (int jj = 0; jj < 4; ++jj)
                if (gj + jj < N_) orow[jj] = acc[ii][jj];
        }
    }
}

extern "C" void kernel_launch(void* const* d_in, const int* in_sizes, int n_in,
                              void* d_out, int out_size, void* d_ws, size_t ws_size,
                              hipStream_t stream) {
    const float* x    = (const float*)d_in[0];
    const float* ew   = (const float*)d_in[1];
    const float* W1   = (const float*)d_in[2];
    const float* W2   = (const float*)d_in[3];
    const int*   erow = (const int*)d_in[4];
    const int*   ecol = (const int*)d_in[5];
    float* out = (float*)d_out;

    // workspace (4B elems): h | h1 | z   (h1,z adjacent -> one zero range)
    float* h  = (float*)d_ws;               // N*H1
    float* h1 = h  + (size_t)N_ * H1_;      // N*H1  (atomic target)
    float* z  = h1 + (size_t)N_ * H1_;      // N*H2  (atomic target)

    gemm_xw1_zero<<<GEMM_BLOCKS + ZERO_BLOCKS, 256, 0, stream>>>(
        x, W1, h, (float4*)h1);
    spmm1_atomic<<<(E_ * H1_ + 255) / 256, 256, 0, stream>>>(h, ew, erow, ecol, h1);
    spmm2_mlp<<<(E_ * H2_ + 255) / 256, 256, 0, stream>>>(h1, W2, ew, erow, ecol, z);

    dim3 grid((N_ + BJ - 1) / BJ, (N_ + BI - 1) / BI);
    zzt<<<grid, 256, 0, stream>>>(z, out);
}

// Round 10
// 195.009 us; speedup vs baseline: 3.0170x; 1.4486x over previous
//
#include <hip/hip_runtime.h>

// GCN autoencoder: recon = (Z @ Z^T)
//   h  = X @ W1   (10000x512 @ 512x32)
//   h1 = relu(A @ h);  h2 = h1 @ W2   (fused, h1 stays in LDS)
//   z  = A @ h2
//   out= z @ z^T  (1e8 f32, 400 MB -> HBM-write-bound, ~58 us floor)
//
// R10 = R9 with the compile fix: __builtin_nontemporal_store needs a native
// clang vector type, not HIP's float4 class. Everything else identical.
// Front-end = EXACT R4. zzt: 64x256 tile, 8x8 outputs/thread; per k: 2 zj
// b128 (contig, conflict-free) + 2 zi b128 broadcast for 64 FMA -> LDS ~21us,
// VALU ~20us, stores 58 -> store-bound. Nontemporal stores skip L2
// write-allocate on the write-once 400MB surface.

constexpr int N_   = 10000;
constexpr int E_   = 320000;
constexpr int F_   = 512;
constexpr int H1_  = 32;
constexpr int H2_  = 16;
constexpr int CAP_ = 96;   // ELL row capacity; P[Poisson(32) > 96] ~ 3e-20

typedef float f32x4 __attribute__((ext_vector_type(4)));

// ---------------- K1: h = X @ W1, side blocks zero cursor ----------------
constexpr int GEMM_BLOCKS = (N_ * H1_) / 256;           // 1250
constexpr int ZERO_BLOCKS = (N_ + 255) / 256;           // 40

__global__ __launch_bounds__(256) void gemm_xw1_zero(const float* __restrict__ x,
                                                     const float* __restrict__ W1,
                                                     float* __restrict__ h,
                                                     int* __restrict__ cursor) {
    if (blockIdx.x >= GEMM_BLOCKS) {
        int i = (blockIdx.x - GEMM_BLOCKS) * 256 + threadIdx.x;
        if (i < N_) cursor[i] = 0;
        return;
    }
    int tid = blockIdx.x * blockDim.x + threadIdx.x;
    int r = tid >> 5;          // /32
    int c = tid & (H1_ - 1);
    const float4* xr = reinterpret_cast<const float4*>(x + (size_t)r * F_);
    float acc = 0.f;
#pragma unroll 8
    for (int k4 = 0; k4 < F_ / 4; ++k4) {
        float4 xv = xr[k4];
        int k = k4 * 4;
        acc = fmaf(xv.x, W1[(k + 0) * H1_ + c], acc);
        acc = fmaf(xv.y, W1[(k + 1) * H1_ + c], acc);
        acc = fmaf(xv.z, W1[(k + 2) * H1_ + c], acc);
        acc = fmaf(xv.w, W1[(k + 3) * H1_ + c], acc);
    }
    h[tid] = acc;
}

// ---------------- K2: scatter edges into ELL rows ----------------
__global__ __launch_bounds__(256) void scatter_ell(const int* __restrict__ erow,
                                                   const int* __restrict__ ecol,
                                                   const float* __restrict__ ew,
                                                   int* __restrict__ cursor,
                                                   int* __restrict__ cole,
                                                   float* __restrict__ we) {
    int e = blockIdx.x * blockDim.x + threadIdx.x;
    if (e >= E_) return;
    int r = erow[e];
    int p = atomicAdd(&cursor[r], 1);
    if (p < CAP_) {                       // overflow-impossible guard
        size_t idx = (size_t)r * CAP_ + p;
        cole[idx] = ecol[e];
        we[idx]   = ew[e];
    }
}

// ---------------- K3: h2 = relu(A @ h) @ W2  (8 rows / block) ----------------
__global__ __launch_bounds__(256) void spmm1_mlp(const float* __restrict__ h,
                                                 const int* __restrict__ cursor,
                                                 const int* __restrict__ cole,
                                                 const float* __restrict__ we,
                                                 const float* __restrict__ W2,
                                                 float* __restrict__ h2) {
    __shared__ float sh1[8][H1_ + 1];
    __shared__ float sW2[H1_ * H2_];
    const int t = threadIdx.x;
    sW2[t]       = W2[t];
    sW2[t + 256] = W2[t + 256];

    const int rl = t >> 5;           // 0..7
    const int f  = t & (H1_ - 1);
    const int r  = blockIdx.x * 8 + rl;
    float acc = 0.f;
    if (r < N_) {
        const int deg = cursor[r];
        const int*   cp = cole + (size_t)r * CAP_;
        const float* wp = we   + (size_t)r * CAP_;
        int p = 0;
        for (; p + 4 <= deg; p += 4) {
            int c0 = cp[p], c1 = cp[p + 1], c2 = cp[p + 2], c3 = cp[p + 3];
            float w0 = wp[p], w1 = wp[p + 1], w2v = wp[p + 2], w3 = wp[p + 3];
            float g0 = h[(size_t)c0 * H1_ + f];
            float g1 = h[(size_t)c1 * H1_ + f];
            float g2 = h[(size_t)c2 * H1_ + f];
            float g3 = h[(size_t)c3 * H1_ + f];
            acc = fmaf(w0, g0, acc);
            acc = fmaf(w1, g1, acc);
            acc = fmaf(w2v, g2, acc);
            acc = fmaf(w3, g3, acc);
        }
        for (; p < deg; ++p)
            acc = fmaf(wp[p], h[(size_t)cp[p] * H1_ + f], acc);
    }
    sh1[rl][f] = fmaxf(acc, 0.f);     // relu fused here
    __syncthreads();

    if (t < 128) {
        const int r2l = t >> 4;       // 0..7
        const int c   = t & (H2_ - 1);
        const int r2  = blockIdx.x * 8 + r2l;
        if (r2 < N_) {
            float a = 0.f;
#pragma unroll
            for (int k = 0; k < H1_; ++k)
                a = fmaf(sh1[r2l][k], sW2[k * H2_ + c], a);
            h2[(size_t)r2 * H2_ + c] = a;
        }
    }
}

// ---------------- K4: z = A @ h2  (16 rows / block) ----------------
__global__ __launch_bounds__(256) void spmm2(const float* __restrict__ h2,
                                             const int* __restrict__ cursor,
                                             const int* __restrict__ cole,
                                             const float* __restrict__ we,
                                             float* __restrict__ z) {
    const int t = threadIdx.x;
    const int rl = t >> 4;            // 0..15
    const int f  = t & (H2_ - 1);
    const int r  = blockIdx.x * 16 + rl;
    if (r >= N_) return;
    const int deg = cursor[r];
    const int*   cp = cole + (size_t)r * CAP_;
    const float* wp = we   + (size_t)r * CAP_;
    float acc = 0.f;
    int p = 0;
    for (; p + 4 <= deg; p += 4) {
        int c0 = cp[p], c1 = cp[p + 1], c2 = cp[p + 2], c3 = cp[p + 3];
        float w0 = wp[p], w1 = wp[p + 1], w2v = wp[p + 2], w3 = wp[p + 3];
        float g0 = h2[(size_t)c0 * H2_ + f];
        float g1 = h2[(size_t)c1 * H2_ + f];
        float g2 = h2[(size_t)c2 * H2_ + f];
        float g3 = h2[(size_t)c3 * H2_ + f];
        acc = fmaf(w0, g0, acc);
        acc = fmaf(w1, g1, acc);
        acc = fmaf(w2v, g2, acc);
        acc = fmaf(w3, g3, acc);
    }
    for (; p < deg; ++p)
        acc = fmaf(wp[p], h2[(size_t)cp[p] * H2_ + f], acc);
    z[(size_t)r * H2_ + f] = acc;
}

// ---------------- K5: out = z @ z^T  (64x256 tile, 8x8 per thread) ---------
constexpr int BI = 64;
constexpr int BJ = 256;

__global__ __launch_bounds__(256) void zzt(const float* __restrict__ z,
                                           float* __restrict__ out) {
    __shared__ float zi[H2_][BI + 4];    // 16 x 68
    __shared__ float zj[H2_][BJ + 8];    // 16 x 264
    const int t  = threadIdx.x;
    const int ib = blockIdx.y * BI;
    const int jb = blockIdx.x * BJ;

    // stage zi: 64 rows x 16k. thread -> (row = t>>2, kq = (t&3)*4)
    {
        int row = t >> 2;
        int kq  = (t & 3) * 4;
        int gr  = ib + row;
        float4 v = (gr < N_)
            ? *reinterpret_cast<const float4*>(z + (size_t)gr * H2_ + kq)
            : make_float4(0.f, 0.f, 0.f, 0.f);
        zi[kq + 0][row] = v.x;
        zi[kq + 1][row] = v.y;
        zi[kq + 2][row] = v.z;
        zi[kq + 3][row] = v.w;
    }
    // stage zj: 256 rows x 16k, 4 iterations
#pragma unroll
    for (int it = 0; it < 4; ++it) {
        int idx = it * 256 + t;
        int row = idx >> 2;
        int kq  = (idx & 3) * 4;
        int gr  = jb + row;
        float4 v = (gr < N_)
            ? *reinterpret_cast<const float4*>(z + (size_t)gr * H2_ + kq)
            : make_float4(0.f, 0.f, 0.f, 0.f);
        zj[kq + 0][row] = v.x;
        zj[kq + 1][row] = v.y;
        zj[kq + 2][row] = v.z;
        zj[kq + 3][row] = v.w;
    }
    __syncthreads();

    const int tj = t & 31;          // 32 j-lanes
    const int i0 = (t >> 5) * 8;    // 8 i-groups of 8 rows

    float4 accA[8] = {};            // j = jb + tj*4 .. +3
    float4 accB[8] = {};            // j = jb + 128 + tj*4 .. +3

#pragma unroll
    for (int k = 0; k < H2_; ++k) {
        float4 b0 = *reinterpret_cast<const float4*>(&zj[k][tj * 4]);
        float4 b1 = *reinterpret_cast<const float4*>(&zj[k][128 + tj * 4]);
        float4 a0 = *reinterpret_cast<const float4*>(&zi[k][i0]);      // bcast
        float4 a1 = *reinterpret_cast<const float4*>(&zi[k][i0 + 4]);  // bcast
        float av[8] = {a0.x, a0.y, a0.z, a0.w, a1.x, a1.y, a1.z, a1.w};
#pragma unroll
        for (int ii = 0; ii < 8; ++ii) {
            accA[ii].x = fmaf(av[ii], b0.x, accA[ii].x);
            accA[ii].y = fmaf(av[ii], b0.y, accA[ii].y);
            accA[ii].z = fmaf(av[ii], b0.z, accA[ii].z);
            accA[ii].w = fmaf(av[ii], b0.w, accA[ii].w);
            accB[ii].x = fmaf(av[ii], b1.x, accB[ii].x);
            accB[ii].y = fmaf(av[ii], b1.y, accB[ii].y);
            accB[ii].z = fmaf(av[ii], b1.z, accB[ii].z);
            accB[ii].w = fmaf(av[ii], b1.w, accB[ii].w);
        }
    }

    const int j0 = jb + tj * 4;
    const int j1 = jb + 128 + tj * 4;
#pragma unroll
    for (int ii = 0; ii < 8; ++ii) {
        int gi = ib + i0 + ii;
        if (gi >= N_) break;
        float* orow = out + (size_t)gi * N_;
        if (j0 + 3 < N_) {
            f32x4 v = {accA[ii].x, accA[ii].y, accA[ii].z, accA[ii].w};
            __builtin_nontemporal_store(v, reinterpret_cast<f32x4*>(orow + j0));
        } else {
            float a[4] = {accA[ii].x, accA[ii].y, accA[ii].z, accA[ii].w};
            for (int jj = 0; jj < 4; ++jj)
                if (j0 + jj < N_) orow[j0 + jj] = a[jj];
        }
        if (j1 + 3 < N_) {
            f32x4 v = {accB[ii].x, accB[ii].y, accB[ii].z, accB[ii].w};
            __builtin_nontemporal_store(v, reinterpret_cast<f32x4*>(orow + j1));
        } else {
            float b[4] = {accB[ii].x, accB[ii].y, accB[ii].z, accB[ii].w};
            for (int jj = 0; jj < 4; ++jj)
                if (j1 + jj < N_) orow[j1 + jj] = b[jj];
        }
    }
}

extern "C" void kernel_launch(void* const* d_in, const int* in_sizes, int n_in,
                              void* d_out, int out_size, void* d_ws, size_t ws_size,
                              hipStream_t stream) {
    const float* x    = (const float*)d_in[0];
    const float* ew   = (const float*)d_in[1];
    const float* W1   = (const float*)d_in[2];
    const float* W2   = (const float*)d_in[3];
    const int*   erow = (const int*)d_in[4];
    const int*   ecol = (const int*)d_in[5];
    float* out = (float*)d_out;

    // workspace layout (4B elements) — same as R4
    float* h      = (float*)d_ws;              // N*H1
    float* h2     = h  + (size_t)N_ * H1_;     // N*H2
    float* z      = h2 + (size_t)N_ * H2_;     // N*H2
    float* we     = z  + (size_t)N_ * H2_;     // N*CAP
    int*   cole   = (int*)(we + (size_t)N_ * CAP_);   // N*CAP
    int*   cursor = cole + (size_t)N_ * CAP_;  // N

    gemm_xw1_zero<<<GEMM_BLOCKS + ZERO_BLOCKS, 256, 0, stream>>>(x, W1, h, cursor);
    scatter_ell<<<(E_ + 255) / 256, 256, 0, stream>>>(erow, ecol, ew, cursor, cole, we);
    spmm1_mlp<<<(N_ + 7) / 8, 256, 0, stream>>>(h, cursor, cole, we, W2, h2);
    spmm2<<<(N_ + 15) / 16, 256, 0, stream>>>(h2, cursor, cole, we, z);

    dim3 grid((N_ + BJ - 1) / BJ, (N_ + BI - 1) / BI);   // 40 x 157
    zzt<<<grid, 256, 0, stream>>>(z, out);
}